// Round 1
// baseline (1722.061 us; speedup 1.0000x reference)
//
#include <hip/hip_runtime.h>
#include <stdint.h>

#define N_ROWS 32768
#define MM 8
#define HIDN 256
#define NCLS 100
#define HALFN 1048576u

// ---------------- threefry2x32 (exact JAX semantics) ----------------
__host__ __device__ inline void tf2x32(uint32_t k0, uint32_t k1, uint32_t x0, uint32_t x1,
                                       uint32_t& o0, uint32_t& o1) {
  uint32_t ks0 = k0, ks1 = k1, ks2 = k0 ^ k1 ^ 0x1BD11BDAu;
  x0 += ks0; x1 += ks1;
#define TFR(r) { x0 += x1; x1 = (x1 << r) | (x1 >> (32 - r)); x1 ^= x0; }
  TFR(13) TFR(15) TFR(26) TFR(6)  x0 += ks1; x1 += ks2 + 1u;
  TFR(17) TFR(29) TFR(16) TFR(24) x0 += ks2; x1 += ks0 + 2u;
  TFR(13) TFR(15) TFR(26) TFR(6)  x0 += ks0; x1 += ks1 + 3u;
  TFR(17) TFR(29) TFR(16) TFR(24) x0 += ks1; x1 += ks2 + 4u;
  TFR(13) TFR(15) TFR(26) TFR(6)  x0 += ks2; x1 += ks0 + 5u;
#undef TFR
  o0 = x0; o1 = x1;
}

__device__ inline float tf_uniform(uint32_t k0, uint32_t k1, uint32_t i) {
  uint32_t o0, o1, b;
  if (i < HALFN) { tf2x32(k0, k1, i, i + HALFN, o0, o1); b = o0; }
  else           { tf2x32(k0, k1, i - HALFN, i, o0, o1); b = o1; }
  return __uint_as_float((b >> 9) | 0x3F800000u) - 1.0f;
}

// template dtype auto-detect: float32 {0,1.0f} / int32 {0,1} / bytes. 4 ones expected.
__device__ inline int load_tmpl(const void* p, int lane) {
  const unsigned* pi = (const unsigned*)p;
  unsigned w = pi[lane];
  unsigned long long okF = __ballot(w == 0u || w == 0x3F800000u);
  unsigned long long onF = __ballot(w == 0x3F800000u);
  unsigned long long okI = __ballot(w <= 1u);
  unsigned long long onI = __ballot(w == 1u);
  if (okF == ~0ull && __popcll(onF) == 4) return (w == 0x3F800000u) ? 1 : 0;
  if (okI == ~0ull && __popcll(onI) == 4) return (int)w;
  const unsigned char* pb = (const unsigned char*)p;
  return pb[lane] ? 1 : 0;
}

// ---------------- stage1: per-row permute, bit-flip masks, targets, y scan ----
__global__ __launch_bounds__(64) void stage1(
    const float* __restrict__ x, const int* __restrict__ y, const int* __restrict__ perm,
    const void* tmap, const void* traw,
    uint32_t km0, uint32_t km1, uint32_t kr0, uint32_t kr1,
    float* __restrict__ xp, float* __restrict__ xm,
    unsigned long long* __restrict__ targ, unsigned long long* __restrict__ xb,
    float* __restrict__ winv, unsigned char* __restrict__ poslist, int* __restrict__ nposA) {
  int n = blockIdx.x;
  int lane = threadIdx.x;
  __shared__ float su[64];
  int tm = load_tmpl(tmap, lane);
  int tr = load_tmpl(traw, lane);
  float xpv = x[n * 64 + perm[lane]];
  uint32_t i = (uint32_t)(n * 64 + lane);

  // map-template flip mask: rank of each lane's uniform, scatter template by rank
  float um = tf_uniform(km0, km1, i);
  su[lane] = um; __syncthreads();
  int rank = 0;
  for (int k = 0; k < 64; k++) { float v = su[k]; rank += (v < um) || (v == um && k < lane); }
  unsigned long long fm = tm ? (1ull << rank) : 0ull;
  for (int off = 1; off < 64; off <<= 1) fm |= __shfl_xor(fm, off);
  __syncthreads();

  float ur = tf_uniform(kr0, kr1, i);
  su[lane] = ur; __syncthreads();
  rank = 0;
  for (int k = 0; k < 64; k++) { float v = su[k]; rank += (v < ur) || (v == ur && k < lane); }
  unsigned long long fr = tr ? (1ull << rank) : 0ull;
  for (int off = 1; off < 64; off <<= 1) fr |= __shfl_xor(fr, off);

  float xmv = ((fm >> lane) & 1ull) ? -xpv : xpv;
  float rfv = ((fr >> lane) & 1ull) ? -xpv : xpv;
  xp[n * 64 + lane] = xpv;
  xm[n * 64 + lane] = xmv;
  unsigned long long t64 = __ballot(rfv > 0.0f);
  unsigned long long b64 = __ballot(xpv > 0.0f);

  int c1 = y[n * NCLS + lane] > 0;
  int c2 = (lane < NCLS - 64) ? (y[n * NCLS + 64 + lane] > 0) : 0;
  unsigned long long p0 = __ballot(c1);
  unsigned long long p1 = __ballot(c2);
  if (lane == 0) {
    targ[n] = t64; xb[n] = b64;
    int cnt = __popcll(p0) + __popcll(p1);
    winv[n] = 1.0f / (float)cnt;
    unsigned char* pl = poslist + (size_t)n * 64;
    int k2 = 0;
    unsigned long long b = p0;
    while (b && k2 < 64) { int c = __ffsll(b) - 1; pl[k2++] = (unsigned char)c; b &= b - 1; }
    b = p1;
    while (b && k2 < 64) { int c = __ffsll(b) - 1; pl[k2++] = (unsigned char)(c + 64); b &= b - 1; }
    nposA[n] = k2;
  }
}

// ---------------- stage2: centroid bits (bytes of cb64 are centerTarget) -----
__global__ void stage2(const float* __restrict__ centroids, const int* __restrict__ perm,
                       unsigned long long* __restrict__ cb64) {
  int c = threadIdx.x;
  if (c >= NCLS) return;
  unsigned long long bits = 0;
  for (int j = 0; j < 64; j++)
    if (centroids[c * 64 + perm[j]] > 0.0f) bits |= (1ull << j);
  cb64[c] = bits;
}

// ---------------- hamming reduction ----------------
__global__ __launch_bounds__(256) void hamk(const int* __restrict__ y,
                                            const unsigned long long* __restrict__ xb,
                                            const unsigned long long* __restrict__ cb64,
                                            float* __restrict__ acc) {
  __shared__ unsigned long long cbs[NCLS];
  __shared__ float cpop[NCLS];
  int tid = threadIdx.x;
  for (int c = tid; c < NCLS; c += 256) { cbs[c] = cb64[c]; cpop[c] = (float)__popcll(cbs[c]); }
  __syncthreads();
  int n = blockIdx.x * 256 + tid;
  unsigned long long xv = xb[n];
  float px = (float)__popcll(xv);
  float hs = 0.0f; float cnt = 0.0f;
  for (int c = 0; c < NCLS; c++) {
    if (y[(size_t)n * NCLS + c] > 0) {
      hs += px + cpop[c] - 2.0f * (float)__popcll(xv & cbs[c]);
      cnt += 1.0f;
    }
  }
  for (int off = 32; off; off >>= 1) { hs += __shfl_down(hs, off); cnt += __shfl_down(cnt, off); }
  if ((tid & 63) == 0) { atomicAdd(&acc[3], hs); atomicAdd(&acc[4], cnt); }
}

// ---------------- fused MLP + loss epilogue ----------------
// grid: (512 row-tiles, m=8, pass: 0=map(flipped) 1=net(plain)); block 256.
__global__ __launch_bounds__(256, 2) void mapnet(
    const float* __restrict__ Xm, const float* __restrict__ Xp,
    const float* __restrict__ W1, const float* __restrict__ B1,
    const float* __restrict__ W2, const float* __restrict__ B2,
    const unsigned long long* __restrict__ targ, const float* __restrict__ winv,
    const unsigned char* __restrict__ poslist, const int* __restrict__ nposA,
    const unsigned long long* __restrict__ cb64,
    float* __restrict__ acc) {
  __shared__ float hs[64][HIDN];  // 64 KB
  int m = blockIdx.y, pass = blockIdx.z;
  int n0 = blockIdx.x * 64;
  const float* Xin = pass ? Xp : Xm;
  int tid = threadIdx.x, lane = tid & 63, wv = tid >> 6;

  // every wave: lane L holds row L's 8 inputs (shfl-broadcast later)
  float xr[8];
  {
    const float* src = Xin + (size_t)(n0 + lane) * 64 + m * 8;
#pragma unroll
    for (int i = 0; i < 8; i++) xr[i] = src[i];
  }
  // H = silu(x @ W1 + b1): thread = column
  {
    int t = tid;
    float w1c[8];
#pragma unroll
    for (int i = 0; i < 8; i++) w1c[i] = W1[((size_t)m * 8 + i) * HIDN + t];
    float bb = B1[m * HIDN + t];
    for (int r = 0; r < 64; r++) {
      float z = bb;
#pragma unroll
      for (int i = 0; i < 8; i++) z += __shfl(xr[i], r) * w1c[i];
      hs[r][t] = z / (1.0f + __expf(-z));
    }
  }
  __syncthreads();

  // logits = H @ W2 + b2. wave wv owns rows wv*16..+15, lane owns cols 4*lane..+3
  int r0 = wv * 16;
  int c0 = lane * 4;
  float a0[16], a1[16], a2[16], a3[16];
#pragma unroll
  for (int q = 0; q < 16; q++) { a0[q] = 0; a1[q] = 0; a2[q] = 0; a3[q] = 0; }
  const float* W2m = W2 + (size_t)m * HIDN * HIDN;
  for (int hh = 0; hh < HIDN; hh += 4) {
    float4 w0 = *(const float4*)(W2m + (size_t)(hh + 0) * HIDN + c0);
    float4 w1 = *(const float4*)(W2m + (size_t)(hh + 1) * HIDN + c0);
    float4 w2 = *(const float4*)(W2m + (size_t)(hh + 2) * HIDN + c0);
    float4 w3 = *(const float4*)(W2m + (size_t)(hh + 3) * HIDN + c0);
#pragma unroll
    for (int q = 0; q < 16; q++) {
      float4 hv = *(const float4*)(&hs[r0 + q][hh]);
      a0[q] += hv.x * w0.x + hv.y * w1.x + hv.z * w2.x + hv.w * w3.x;
      a1[q] += hv.x * w0.y + hv.y * w1.y + hv.z * w2.y + hv.w * w3.y;
      a2[q] += hv.x * w0.z + hv.y * w1.z + hv.z * w2.z + hv.w * w3.z;
      a3[q] += hv.x * w0.w + hv.y * w1.w + hv.z * w2.w + hv.w * w3.w;
    }
  }
  float4 b2v = *(const float4*)(B2 + m * HIDN + c0);
#pragma unroll
  for (int q = 0; q < 16; q++) { a0[q] += b2v.x; a1[q] += b2v.y; a2[q] += b2v.z; a3[q] += b2v.w; }

  float partLoss = 0.0f, partHit = 0.0f;
#pragma unroll
  for (int q = 0; q < 16; q++) {
    int n = n0 + r0 + q;
    // row max + first-index argmax
    float mv = a0[q]; int mi = c0;
    if (a1[q] > mv) { mv = a1[q]; mi = c0 + 1; }
    if (a2[q] > mv) { mv = a2[q]; mi = c0 + 2; }
    if (a3[q] > mv) { mv = a3[q]; mi = c0 + 3; }
    for (int off = 32; off; off >>= 1) {
      float om = __shfl_xor(mv, off);
      int oi = __shfl_xor(mi, off);
      if (om > mv || (om == mv && oi < mi)) { mv = om; mi = oi; }
    }
    float s = __expf(a0[q] - mv) + __expf(a1[q] - mv) + __expf(a2[q] - mv) + __expf(a3[q] - mv);
    for (int off = 32; off; off >>= 1) s += __shfl_xor(s, off);
    float lse = mv + __logf(s);
    if (pass == 0) {
      int t = (int)((targ[n] >> (m * 8)) & 0xFFull);
      int k = t & 3;
      float pv = (k == 0) ? a0[q] : (k == 1) ? a1[q] : (k == 2) ? a2[q] : a3[q];
      float picked = __shfl(pv, t >> 2);
      partLoss += lse - picked;
      partHit += (mi == t) ? 1.0f : 0.0f;
    } else {
      int np = nposA[n];
      float wv_ = winv[n];
      const unsigned char* pl = poslist + (size_t)n * 64;
      float sp = 0.0f;
      for (int j = 0; j < np; j++) {
        int c = pl[j];
        int t = (int)((cb64[c] >> (m * 8)) & 0xFFull);
        int k = t & 3;
        float pv = (k == 0) ? a0[q] : (k == 1) ? a1[q] : (k == 2) ? a2[q] : a3[q];
        sp += __shfl(pv, t >> 2);
      }
      partLoss += lse - wv_ * sp;
    }
  }
  if (lane == 0) {
    if (pass == 0) { atomicAdd(&acc[0], partLoss); atomicAdd(&acc[2], partHit); }
    else           { atomicAdd(&acc[1], partLoss); }
  }
}

__global__ void finalk(const float* __restrict__ acc, float* __restrict__ out) {
  float netLoss = acc[1] / (float)N_ROWS;
  float mapLoss = acc[0] / (float)N_ROWS;
  out[0] = netLoss + mapLoss;
  out[1] = netLoss;
  out[2] = mapLoss;
  out[3] = acc[2] / (float)(N_ROWS * MM);
  out[4] = acc[3] / acc[4];
}

extern "C" void kernel_launch(void* const* d_in, const int* in_sizes, int n_in,
                              void* d_out, int out_size, void* d_ws, size_t ws_size,
                              hipStream_t stream) {
  const float* x = (const float*)d_in[0];
  const int* y = (const int*)d_in[1];
  const float* centroids = (const float*)d_in[2];
  const int* perm = (const int*)d_in[3];
  const void* tmap = d_in[4];
  const void* traw = d_in[5];
  const float* W1 = (const float*)d_in[6];
  const float* B1 = (const float*)d_in[7];
  const float* W2 = (const float*)d_in[8];
  const float* B2 = (const float*)d_in[9];
  float* out = (float*)d_out;

  char* w = (char*)d_ws;
  float* acc = (float*)w;                                     // 5 floats (256 B reserved)
  float* xp = (float*)(w + 256);                              // 8 MB
  float* xm = xp + (size_t)N_ROWS * 64;                       // 8 MB
  unsigned long long* targ = (unsigned long long*)(xm + (size_t)N_ROWS * 64);  // 256 KB
  unsigned long long* xb = targ + N_ROWS;                     // 256 KB
  unsigned long long* cb64 = xb + N_ROWS;                     // 1 KB (128 slots)
  float* winv = (float*)(cb64 + 128);                         // 128 KB
  int* nposA = (int*)(winv + N_ROWS);                         // 128 KB
  unsigned char* poslist = (unsigned char*)(nposA + N_ROWS);  // 2 MB

  hipMemsetAsync(acc, 0, 64, stream);

  // jax.random.key(1) -> (0,1); split -> kmap=(w0(0,2), w0(1,3)), kraw=(w1(0,2), w1(1,3))
  uint32_t a0, b0, a1, b1;
  tf2x32(0u, 1u, 0u, 2u, a0, b0);
  tf2x32(0u, 1u, 1u, 3u, a1, b1);

  stage1<<<N_ROWS, 64, 0, stream>>>(x, y, perm, tmap, traw, a0, a1, b0, b1,
                                    xp, xm, targ, xb, winv, poslist, nposA);
  stage2<<<1, 128, 0, stream>>>(centroids, perm, cb64);
  hamk<<<N_ROWS / 256, 256, 0, stream>>>(y, xb, cb64, acc);
  dim3 g(N_ROWS / 64, MM, 2);
  mapnet<<<g, 256, 0, stream>>>(xm, xp, W1, B1, W2, B2, targ, winv, poslist, nposA, cb64, acc);
  finalk<<<1, 1, 0, stream>>>(acc, out);
}

// Round 2
// 1027.657 us; speedup vs baseline: 1.6757x; 1.6757x over previous
//
#include <hip/hip_runtime.h>
#include <stdint.h>

#define NR 32768
#define MM 8
#define NCLS 100
#define HALFN 1048576u
#define HSS 260   // ushort stride for h rows (bank-friendly, 8B-aligned)
#define LGS 260   // float stride for logit rows

typedef __bf16 bf4 __attribute__((ext_vector_type(4)));
typedef __bf16 bf8 __attribute__((ext_vector_type(8)));
typedef float f4 __attribute__((ext_vector_type(4)));
typedef unsigned long long ull;

// ---------------- threefry2x32 (exact JAX semantics) ----------------
__host__ __device__ inline void tf2x32(uint32_t k0, uint32_t k1, uint32_t x0, uint32_t x1,
                                       uint32_t& o0, uint32_t& o1) {
  uint32_t ks0 = k0, ks1 = k1, ks2 = k0 ^ k1 ^ 0x1BD11BDAu;
  x0 += ks0; x1 += ks1;
#define TFR(r) { x0 += x1; x1 = (x1 << r) | (x1 >> (32 - r)); x1 ^= x0; }
  TFR(13) TFR(15) TFR(26) TFR(6)  x0 += ks1; x1 += ks2 + 1u;
  TFR(17) TFR(29) TFR(16) TFR(24) x0 += ks2; x1 += ks0 + 2u;
  TFR(13) TFR(15) TFR(26) TFR(6)  x0 += ks0; x1 += ks1 + 3u;
  TFR(17) TFR(29) TFR(16) TFR(24) x0 += ks1; x1 += ks2 + 4u;
  TFR(13) TFR(15) TFR(26) TFR(6)  x0 += ks2; x1 += ks0 + 5u;
#undef TFR
  o0 = x0; o1 = x1;
}

__device__ inline float tf_uniform(uint32_t k0, uint32_t k1, uint32_t i) {
  uint32_t o0, o1, b;
  if (i < HALFN) { tf2x32(k0, k1, i, i + HALFN, o0, o1); b = o0; }
  else           { tf2x32(k0, k1, i - HALFN, i, o0, o1); b = o1; }
  return __uint_as_float((b >> 9) | 0x3F800000u) - 1.0f;
}

// template dtype auto-detect: float32 {0,1.0f} / int32 {0,1} / bytes. 4 ones expected.
__device__ inline int load_tmpl(const void* p, int lane) {
  const unsigned* pi = (const unsigned*)p;
  unsigned w = pi[lane];
  unsigned long long okF = __ballot(w == 0u || w == 0x3F800000u);
  unsigned long long onF = __ballot(w == 0x3F800000u);
  unsigned long long okI = __ballot(w <= 1u);
  unsigned long long onI = __ballot(w == 1u);
  if (okF == ~0ull && __popcll(onF) == 4) return (w == 0x3F800000u) ? 1 : 0;
  if (okI == ~0ull && __popcll(onI) == 4) return (int)w;
  const unsigned char* pb = (const unsigned char*)p;
  return pb[lane] ? 1 : 0;
}

__device__ inline float rdlane(float v, int l) {
  return __int_as_float(__builtin_amdgcn_readlane(__float_as_int(v), l));
}

// ---------------- pack W2 into MFMA B-fragment order, bf16 hi + lo ----------
// dest idx = ((((m*8 + kt)*16 + NT)*64) + lane)*8 + j ; element = W2[m][kt*32+(lane>>4)*8+j][NT*16+(lane&15)]
__global__ __launch_bounds__(256) void packW2(const float* __restrict__ W2, ushort* __restrict__ Wp) {
  int idx = blockIdx.x * 256 + threadIdx.x;   // source index: m*65536 + k*256 + c
  int c = idx & 255, k = (idx >> 8) & 255, m = idx >> 16;
  float v = W2[idx];
  int kt = k >> 5, q = (k >> 3) & 3, j = k & 7;
  int NT = c >> 4, lr = c & 15;
  int didx = ((((m * 8 + kt) * 16 + NT) * 64) + q * 16 + lr) * 8 + j;
  union { __bf16 b; ushort u; } cv;
  __bf16 hi = (__bf16)v;
  cv.b = hi; Wp[didx] = cv.u;
  cv.b = (__bf16)(v - (float)hi); Wp[(1 << 19) + didx] = cv.u;
}

// ---------------- stage2: centroid bits ----------------
__global__ void stage2(const float* __restrict__ centroids, const int* __restrict__ perm,
                       ull* __restrict__ cb64) {
  int c = threadIdx.x;
  if (c >= 128) return;
  ull bits = 0;
  if (c < NCLS)
    for (int j = 0; j < 64; j++)
      if (centroids[c * 64 + perm[j]] > 0.0f) bits |= (1ull << j);
  cb64[c] = bits;
}

// ---------------- stage1: permute, flips, targets, y scan, hamming -----------
__global__ __launch_bounds__(256) void stage1(
    const float* __restrict__ x, const int* __restrict__ y, const int* __restrict__ perm,
    const void* tmap, const void* traw,
    uint32_t km0, uint32_t km1, uint32_t kr0, uint32_t kr1,
    float* __restrict__ xp, float* __restrict__ xm,
    ull* __restrict__ targ, const ull* __restrict__ cb64,
    float* __restrict__ winv, unsigned char* __restrict__ poslist, int* __restrict__ nposA,
    float* __restrict__ acc) {
  int wv = threadIdx.x >> 6, lane = threadIdx.x & 63;
  int n = blockIdx.x * 4 + wv;
  __shared__ float shh[2];
  if (threadIdx.x == 0) { shh[0] = 0.0f; shh[1] = 0.0f; }
  __syncthreads();

  int tm = load_tmpl(tmap, lane);
  int tr = load_tmpl(traw, lane);
  float xpv = x[n * 64 + perm[lane]];
  uint32_t i = (uint32_t)(n * 64 + lane);

  float um = tf_uniform(km0, km1, i);
  int rank = 0;
  for (int k = 0; k < 64; k++) {
    float vk = rdlane(um, k);
    rank += (vk < um) || (vk == um && k < lane);
  }
  ull fm = tm ? (1ull << rank) : 0ull;
  for (int off = 1; off < 64; off <<= 1) fm |= __shfl_xor(fm, off);

  float ur = tf_uniform(kr0, kr1, i);
  rank = 0;
  for (int k = 0; k < 64; k++) {
    float vk = rdlane(ur, k);
    rank += (vk < ur) || (vk == ur && k < lane);
  }
  ull fr = tr ? (1ull << rank) : 0ull;
  for (int off = 1; off < 64; off <<= 1) fr |= __shfl_xor(fr, off);

  float xmv = ((fm >> lane) & 1ull) ? -xpv : xpv;
  float rfv = ((fr >> lane) & 1ull) ? -xpv : xpv;
  xp[n * 64 + lane] = xpv;
  xm[n * 64 + lane] = xmv;
  ull t64 = __ballot(rfv > 0.0f);
  ull b64v = __ballot(xpv > 0.0f);

  int c1 = y[(size_t)n * NCLS + lane] > 0;
  int c2 = (lane < NCLS - 64) ? (y[(size_t)n * NCLS + 64 + lane] > 0) : 0;
  ull p0 = __ballot(c1);
  ull p1 = __ballot(c2);
  float cnt = (float)(__popcll(p0) + __popcll(p1));

  // hamming contribution (fused old hamk)
  float px = (float)__popcll(b64v);
  float hsum = 0.0f;
  if (c1) { ull cb = cb64[lane]; hsum += px + (float)__popcll(cb) - 2.0f * (float)__popcll(b64v & cb); }
  if (c2) { ull cb = cb64[64 + lane]; hsum += px + (float)__popcll(cb) - 2.0f * (float)__popcll(b64v & cb); }
  for (int off = 1; off < 64; off <<= 1) hsum += __shfl_xor(hsum, off);

  if (lane == 0) {
    targ[n] = t64;
    winv[n] = 1.0f / cnt;
    unsigned char* pl = poslist + (size_t)n * 64;
    int k2 = 0;
    ull b = p0;
    while (b && k2 < 64) { int c = __ffsll(b) - 1; pl[k2++] = (unsigned char)c; b &= b - 1; }
    b = p1;
    while (b && k2 < 64) { int c = __ffsll(b) - 1; pl[k2++] = (unsigned char)(c + 64); b &= b - 1; }
    nposA[n] = k2;
    atomicAdd(&shh[0], hsum);
    atomicAdd(&shh[1], cnt);
  }
  __syncthreads();
  if (threadIdx.x == 0) { atomicAdd(&acc[3], shh[0]); atomicAdd(&acc[4], shh[1]); }
}

__device__ inline bf8 ld8(const ushort* p) {
  bf4 a = *(const bf4*)p;
  bf4 b = *(const bf4*)(p + 4);
  return __builtin_shufflevector(a, b, 0, 1, 2, 3, 4, 5, 6, 7);
}

// ---------------- fused MLP (bf16 MFMA) + loss epilogue ----------------
// grid (512, 8, 2); block 256. pass0 = map (split-precision 3x MFMA), pass1 = net.
__global__ __launch_bounds__(256, 2) void mapnet2(
    const float* __restrict__ Xm, const float* __restrict__ Xp,
    const float* __restrict__ W1, const float* __restrict__ B1,
    const ushort* __restrict__ Wp, const float* __restrict__ B2,
    const ull* __restrict__ targ, const float* __restrict__ winv,
    const unsigned char* __restrict__ poslist, const int* __restrict__ nposA,
    const ull* __restrict__ cb64, float* __restrict__ accg) {
  __shared__ union {
    ushort hs[2 * 64 * HSS];   // [ver][row][col] bf16 h (hi, lo)
    float lg[32 * LGS];        // 32-row logit staging (aliases hs_hi; used after K-loop)
  } u;
  const int tid = threadIdx.x, lane = tid & 63, wv = tid >> 6;
  const int m = blockIdx.y, pass = blockIdx.z;
  const int n0 = blockIdx.x * 64;
  const float* Xin = pass ? Xp : Xm;

  // ---- layer 1: thread = column, rows via readlane ----
  {
    const float* src = Xin + (size_t)(n0 + lane) * 64 + m * 8;
    f4 x0 = *(const f4*)src;
    f4 x1 = *(const f4*)(src + 4);
    float xr[8] = {x0.x, x0.y, x0.z, x0.w, x1.x, x1.y, x1.z, x1.w};
    float w1c[8];
#pragma unroll
    for (int i = 0; i < 8; i++) w1c[i] = W1[(size_t)(m * 8 + i) * 256 + tid];
    float bb = B1[m * 256 + tid];
    for (int r = 0; r < 64; r++) {
      float z = bb;
#pragma unroll
      for (int i = 0; i < 8; i++) z += rdlane(xr[i], r) * w1c[i];
      float h = z / (1.0f + __expf(-z));
      union { __bf16 b; ushort us; } cv;
      __bf16 hi = (__bf16)h;
      cv.b = hi;
      u.hs[r * HSS + tid] = cv.us;
      if (pass == 0) {
        cv.b = (__bf16)(h - (float)hi);
        u.hs[64 * HSS + r * HSS + tid] = cv.us;
      }
    }
  }
  __syncthreads();

  // ---- K loop: wave wv owns cols wv*64..+63 (NT = wv*4+nt), rows rt*16 ----
  const int q = lane >> 4, lr = lane & 15;
  f4 acc4[4][4];
#pragma unroll
  for (int rt = 0; rt < 4; rt++)
#pragma unroll
    for (int nt = 0; nt < 4; nt++) acc4[rt][nt] = (f4){0.f, 0.f, 0.f, 0.f};

  const size_t wbase = (size_t)m * 8 * 16 * 64 * 8;
  for (int kt = 0; kt < 8; kt++) {
    bf8 ah[4], al[4];
#pragma unroll
    for (int rt = 0; rt < 4; rt++) {
      int off = (rt * 16 + lr) * HSS + kt * 32 + q * 8;
      ah[rt] = ld8(u.hs + off);
      if (pass == 0) al[rt] = ld8(u.hs + 64 * HSS + off);
    }
#pragma unroll
    for (int nt = 0; nt < 4; nt++) {
      const ushort* bp = Wp + wbase + (((size_t)kt * 16 + (wv * 4 + nt)) * 64 + lane) * 8;
      bf8 bh = *(const bf8*)bp;
      if (pass == 0) {
        bf8 bl = *(const bf8*)(bp + (1 << 19));
#pragma unroll
        for (int rt = 0; rt < 4; rt++) {
          acc4[rt][nt] = __builtin_amdgcn_mfma_f32_16x16x32_bf16(ah[rt], bh, acc4[rt][nt], 0, 0, 0);
          acc4[rt][nt] = __builtin_amdgcn_mfma_f32_16x16x32_bf16(al[rt], bh, acc4[rt][nt], 0, 0, 0);
          acc4[rt][nt] = __builtin_amdgcn_mfma_f32_16x16x32_bf16(ah[rt], bl, acc4[rt][nt], 0, 0, 0);
        }
      } else {
#pragma unroll
        for (int rt = 0; rt < 4; rt++)
          acc4[rt][nt] = __builtin_amdgcn_mfma_f32_16x16x32_bf16(ah[rt], bh, acc4[rt][nt], 0, 0, 0);
      }
    }
  }

  float bv[4];
#pragma unroll
  for (int nt = 0; nt < 4; nt++) bv[nt] = B2[m * 256 + wv * 64 + nt * 16 + lr];

  // ---- epilogue: two 32-row phases through LDS ----
  float partLoss = 0.0f, partHit = 0.0f;
  for (int ph = 0; ph < 2; ph++) {
    __syncthreads();  // hs reads (ph0) / prior epilogue reads (ph1) complete
#pragma unroll
    for (int rt2 = 0; rt2 < 2; rt2++) {
      int rt = ph * 2 + rt2;
#pragma unroll
      for (int nt = 0; nt < 4; nt++)
#pragma unroll
        for (int reg = 0; reg < 4; reg++) {
          int row = rt2 * 16 + q * 4 + reg;                 // local 0..31
          u.lg[row * LGS + wv * 64 + nt * 16 + lr] = acc4[rt][nt][reg] + bv[nt];
        }
    }
    __syncthreads();
    int rl = wv * 8 + (lane >> 3);       // local row 0..31
    int n = n0 + ph * 32 + rl;
    int cj = lane & 7;                   // 8 lanes per row
    const float* lrow = u.lg + rl * LGS;
    if (pass == 0) {
      float mv = -1e30f; int mi = 0;
      for (int k2 = 0; k2 < 32; k2++) {
        int c = cj + (k2 << 3);
        float v = lrow[c];
        if (v > mv) { mv = v; mi = c; }
      }
      for (int off = 1; off < 8; off <<= 1) {
        float om = __shfl_xor(mv, off); int oi = __shfl_xor(mi, off);
        if (om > mv || (om == mv && oi < mi)) { mv = om; mi = oi; }
      }
      float s = 0.0f;
      for (int k2 = 0; k2 < 32; k2++) s += __expf(lrow[cj + (k2 << 3)] - mv);
      for (int off = 1; off < 8; off <<= 1) s += __shfl_xor(s, off);
      float lse = mv + __logf(s);
      int t = (int)((targ[n] >> (m * 8)) & 0xFFull);
      partLoss += lse - lrow[t];
      partHit += (mi == t) ? 1.0f : 0.0f;
    } else {
      float s = 0.0f;
      for (int k2 = 0; k2 < 32; k2++) s += __expf(lrow[cj + (k2 << 3)]);
      for (int off = 1; off < 8; off <<= 1) s += __shfl_xor(s, off);
      float lse = __logf(s);
      int np = nposA[n];
      const unsigned char* pl = poslist + (size_t)n * 64;
      float sp = 0.0f;
      for (int j2 = cj; j2 < np; j2 += 8) {
        int c = pl[j2];
        int t = (int)((cb64[c] >> (m * 8)) & 0xFFull);
        sp += lrow[t];
      }
      for (int off = 1; off < 8; off <<= 1) sp += __shfl_xor(sp, off);
      partLoss += lse - winv[n] * sp;
    }
  }
  for (int off = 8; off < 64; off <<= 1) {
    partLoss += __shfl_xor(partLoss, off);
    partHit += __shfl_xor(partHit, off);
  }
  if (lane == 0) {
    if (pass == 0) { atomicAdd(&accg[0], partLoss); atomicAdd(&accg[2], partHit); }
    else           { atomicAdd(&accg[1], partLoss); }
  }
}

__global__ void finalk(const float* __restrict__ acc, float* __restrict__ out) {
  float netLoss = acc[1] / (float)NR;
  float mapLoss = acc[0] / (float)NR;
  out[0] = netLoss + mapLoss;
  out[1] = netLoss;
  out[2] = mapLoss;
  out[3] = acc[2] / (float)(NR * MM);
  out[4] = acc[3] / acc[4];
}

extern "C" void kernel_launch(void* const* d_in, const int* in_sizes, int n_in,
                              void* d_out, int out_size, void* d_ws, size_t ws_size,
                              hipStream_t stream) {
  const float* x = (const float*)d_in[0];
  const int* y = (const int*)d_in[1];
  const float* centroids = (const float*)d_in[2];
  const int* perm = (const int*)d_in[3];
  const void* tmap = d_in[4];
  const void* traw = d_in[5];
  const float* W1 = (const float*)d_in[6];
  const float* B1 = (const float*)d_in[7];
  const float* W2 = (const float*)d_in[8];
  const float* B2 = (const float*)d_in[9];
  float* out = (float*)d_out;

  char* w = (char*)d_ws;
  float* acc = (float*)w;                                     // 256 B reserved
  float* xp = (float*)(w + 256);                              // 8 MB
  float* xm = xp + (size_t)NR * 64;                           // 8 MB
  ull* targ = (ull*)(xm + (size_t)NR * 64);                   // 256 KB
  ull* cb64 = targ + NR;                                      // 1 KB (128 slots)
  float* winv = (float*)(cb64 + 128);                         // 128 KB
  int* nposA = (int*)(winv + NR);                             // 128 KB
  unsigned char* poslist = (unsigned char*)(nposA + NR);      // 2 MB
  ushort* Wp = (ushort*)(poslist + (size_t)NR * 64);          // 2 MB (hi + lo)

  hipMemsetAsync(acc, 0, 64, stream);

  // jax.random.key(1) -> (0,1); split -> kmap=(w0(0,2), w0(1,3)), kraw=(w1(0,2), w1(1,3))
  uint32_t a0, b0, a1, b1;
  tf2x32(0u, 1u, 0u, 2u, a0, b0);
  tf2x32(0u, 1u, 1u, 3u, a1, b1);

  packW2<<<2048, 256, 0, stream>>>(W2, Wp);
  stage2<<<1, 128, 0, stream>>>(centroids, perm, cb64);
  stage1<<<NR / 4, 256, 0, stream>>>(x, y, perm, tmap, traw, a0, a1, b0, b1,
                                     xp, xm, targ, cb64, winv, poslist, nposA, acc);
  dim3 g(NR / 64, MM, 2);
  mapnet2<<<g, 256, 0, stream>>>(xm, xp, W1, B1, Wp, B2, targ, winv, poslist, nposA, cb64, acc);
  finalk<<<1, 1, 0, stream>>>(acc, out);
}